// Round 4
// baseline (162.409 us; speedup 1.0000x reference)
//
#include <hip/hip_runtime.h>
#include <stdint.h>

#define SAMPLES   524288
#define BATCH     16
#define T_FRAMES  2048
#define K_FFT     1024
#define HOPSZ     256
#define CACHEPAD  1023
#define NCH       513
#define XROW      525312               // 1023 pad + 524288 samples + 1 spare (16B-aligned rows)

typedef __bf16          bf16x8 __attribute__((ext_vector_type(8)));
typedef float           f32x4  __attribute__((ext_vector_type(4)));
typedef float           f32x16 __attribute__((ext_vector_type(16)));
typedef unsigned short  u16x8  __attribute__((ext_vector_type(8)));

__device__ __forceinline__ unsigned short f2bf(float f) {
    union { float f; unsigned u; } v; v.f = f;
    unsigned r = v.u + 0x7fffu + ((v.u >> 16) & 1u);   // round-to-nearest-even
    return (unsigned short)(r >> 16);
}

// ---------- fused prep ----------------------------------------------------
// blocks [0,512):    weight fp32 -> bf16, M=1024 layout: per 32-row group q:
//                    {16 cos rows of bins q*16+r | 16 sin rows}; sin(bin0)
//                    slot holds cos(bin 512) (sin0 == 0, sin512 == 0).
// blocks [512,4608): x fp32 -> bf16, 1023-zero left pad. Store window shifted
//                    +1 sample so dst is 16B-aligned -> one u16x8 store per
//                    thread (sample 0 scalar once per row; tail writes the
//                    never-read spare slot).
__global__ void prep(const float* __restrict__ x, const float* __restrict__ wsrc,
                     unsigned short* __restrict__ Xb, unsigned short* __restrict__ Wb) {
    const int bid = blockIdx.x;
    const int tid = threadIdx.x;
    if (bid < 512) {
        int gid = bid * 256 + tid;            // 0..131071, 8 u16 each
        int m   = gid >> 7;                   // 0..1023 output row
        int kc  = (gid & 127) << 3;           // k chunk base
        int q = m >> 5, h = (m >> 4) & 1, r = m & 15;
        int bin  = q * 16 + r;
        int srow = (h == 0) ? bin : (bin == 0 ? 512 : NCH + bin);
        const float* s = wsrc + (long long)srow * K_FFT + kc;
        f32x4 a = *(const f32x4*)s;
        f32x4 c = *(const f32x4*)(s + 4);
        union { u16x8 v; unsigned short e[8]; } o;
        o.e[0]=f2bf(a[0]); o.e[1]=f2bf(a[1]); o.e[2]=f2bf(a[2]); o.e[3]=f2bf(a[3]);
        o.e[4]=f2bf(c[0]); o.e[5]=f2bf(c[1]); o.e[6]=f2bf(c[2]); o.e[7]=f2bf(c[3]);
        *(u16x8*)(Wb + (long long)m * K_FFT + kc) = o.v;
    } else {
        int id  = bid - 512;
        int bat = id >> 8;
        int bx  = id & 255;
        unsigned short* xbo = Xb + (long long)bat * XROW;
        if (bx == 0) {
            for (int j = tid; j < CACHEPAD; j += 256) xbo[j] = 0;
        }
        int i0 = (bx * 256 + tid) * 8;
        const float* xb = x + (long long)bat * SAMPLES;
        f32x4 a = *(const f32x4*)&xb[i0];
        f32x4 c = *(const f32x4*)&xb[i0 + 4];
        float e = (i0 + 8 < SAMPLES) ? xb[i0 + 8] : 0.f;
        union { u16x8 v; unsigned short s[8]; } o;     // samples i0+1 .. i0+8
        o.s[0]=f2bf(a[1]); o.s[1]=f2bf(a[2]); o.s[2]=f2bf(a[3]);
        o.s[3]=f2bf(c[0]); o.s[4]=f2bf(c[1]); o.s[5]=f2bf(c[2]); o.s[6]=f2bf(c[3]);
        o.s[7]=f2bf(e);
        *(u16x8*)(xbo + 1024 + i0) = o.v;              // byte off 2048+16k: aligned
        if (i0 == 0) xbo[CACHEPAD] = f2bf(a[0]);       // sample 0
    }
}

// ---------- async global -> LDS (16 B/lane, dst = wave-uniform base + lane*16)
__device__ __forceinline__ void gll16(const unsigned short* g, unsigned short* s) {
    __builtin_amdgcn_global_load_lds(
        (const __attribute__((address_space(1))) void*)g,
        (__attribute__((address_space(3))) void*)s,
        16, 0, 0);
}

// ---------- main GEMM + magnitude epilogue --------------------------------
// Round-2 base (954 TF, high-TLP 2-barrier 128x128 tile, ~2-3 blocks/CU),
// with the MFMA shape swapped 16x16x32 -> 32x32x16: half the MFMA issue
// slots per FLOP, higher pipe ceiling (m119: 2495 vs 2176 TF), identical
// LDS layout/swizzle/staging/ds_read count. Wave tile 64x64 = 2x2 frags of
// 32x32. C/D: col=lane&31, row=(reg&3)+8*(reg>>2)+4*(lane>>5) -> cos row m
// in reg r<8 pairs with sin row m+16 in reg r+8 LANE-LOCALLY; stores are
// full 128B lines (32 consecutive frames).
__global__ __launch_bounds__(256, 3)
void stft_gemm(const unsigned short* __restrict__ Xb,
               const unsigned short* __restrict__ Wb,
               float* __restrict__ out) {
    __shared__ unsigned short Ws[128 * 64];   // 16 KB
    __shared__ unsigned short Fs[128 * 64];   // 16 KB

    const int id  = blockIdx.x;
    const int xcd = id & 7;
    const int idx = id >> 3;        // 0..255
    const int nt  = idx >> 5;       // 0..7  M tile (32 consecutive blocks share it)
    const int ft  = (xcd << 5) | (idx & 31);   // 0..255 frame tile, striped per XCD

    const int tid = threadIdx.x;
    const int l   = tid & 63;
    const int w   = tid >> 6;

    const int b  = ft >> 4;
    const int t0 = (ft & 15) * 128;            // frame tile never crosses a batch

    const unsigned short* xbase = Xb + (long long)b * XROW;

    // ---- staging: wave w stages rows [w*32, w*32+32) of Fs and Ws,
    //      4 gll16 calls each; call c: row = w*32 + c*8 + (l>>3),
    //      lds chunk = l&7 (implicit dst), global chunk = (l&7) ^ (row&7).
    const int srow   = l >> 3;
    const int schunk = l & 7;

    const unsigned short* fsrc[4];
    const unsigned short* wsrc[4];
    unsigned short* fdst[4];
    unsigned short* wdst[4];
    #pragma unroll
    for (int c = 0; c < 4; ++c) {
        int r = w * 32 + c * 8 + srow;
        int gchunk = schunk ^ (r & 7);
        fsrc[c] = xbase + (t0 + r) * HOPSZ + gchunk * 8;       // frame r, k-chunk
        wsrc[c] = Wb + ((long long)(nt * 128 + r)) * K_FFT + gchunk * 8;
        fdst[c] = Fs + (w * 32 + c * 8) * 64;
        wdst[c] = Ws + (w * 32 + c * 8) * 64;
    }

    const int wave_m = w & 1;
    const int wave_n = w >> 1;
    const int l31 = l & 31;
    const int lh  = l >> 5;

    f32x16 acc[2][2];
    #pragma unroll
    for (int i = 0; i < 2; ++i)
        #pragma unroll
        for (int j = 0; j < 2; ++j)
            acc[i][j] = (f32x16){0.f,0.f,0.f,0.f,0.f,0.f,0.f,0.f,
                                 0.f,0.f,0.f,0.f,0.f,0.f,0.f,0.f};

    // ds_read offsets: A row = wave_m*64 + i*32 + l31 (row&7 == l&7);
    // wanted global chunk = s*2 + lh -> lds chunk = (s*2+lh) ^ (l&7).
    int a_off[2][4], b_off[2][4];
    #pragma unroll
    for (int i = 0; i < 2; ++i)
        #pragma unroll
        for (int s = 0; s < 4; ++s) {
            int ck = (((s * 2 + lh) ^ (l & 7))) * 8;
            a_off[i][s] = (wave_m * 64 + i * 32 + l31) * 64 + ck;
            b_off[i][s] = (wave_n * 64 + i * 32 + l31) * 64 + ck;
        }

    for (int kk = 0; kk < K_FFT; kk += 64) {
        #pragma unroll
        for (int c = 0; c < 4; ++c) gll16(fsrc[c] + kk, fdst[c]);
        #pragma unroll
        for (int c = 0; c < 4; ++c) gll16(wsrc[c] + kk, wdst[c]);
        __syncthreads();

        #pragma unroll
        for (int s = 0; s < 4; ++s) {          // 4 k-slices of 16
            bf16x8 a0 = *(const bf16x8*)&Ws[a_off[0][s]];
            bf16x8 a1 = *(const bf16x8*)&Ws[a_off[1][s]];
            bf16x8 b0 = *(const bf16x8*)&Fs[b_off[0][s]];
            bf16x8 b1 = *(const bf16x8*)&Fs[b_off[1][s]];
            acc[0][0] = __builtin_amdgcn_mfma_f32_32x32x16_bf16(a0, b0, acc[0][0], 0, 0, 0);
            acc[0][1] = __builtin_amdgcn_mfma_f32_32x32x16_bf16(a0, b1, acc[0][1], 0, 0, 0);
            acc[1][0] = __builtin_amdgcn_mfma_f32_32x32x16_bf16(a1, b0, acc[1][0], 0, 0, 0);
            acc[1][1] = __builtin_amdgcn_mfma_f32_32x32x16_bf16(a1, b1, acc[1][1], 0, 0, 0);
        }
        __syncthreads();
    }

    // ---- epilogue: mag = sqrt(max(re^2+im^2, 1e-12)) ----------------------
    // frag (i,j): 32-row group = nt*4 + wave_m*2 + i ({16 cos | 16 sin});
    // lane: frame = l31, reg r<8: cos row mloc=(r&3)+8*(r>>2)+4*lh,
    // reg r+8: sin row mloc+16. bin0 slot: re->bin0, im(=cos512)->bin512.
    float* outb = out + (long long)b * (NCH * T_FRAMES);
    #pragma unroll
    for (int i = 0; i < 2; ++i) {
        const int group = nt * 4 + wave_m * 2 + i;
        #pragma unroll
        for (int j = 0; j < 2; ++j) {
            const int t = t0 + wave_n * 64 + j * 32 + l31;
            #pragma unroll
            for (int r = 0; r < 8; ++r) {
                const int mloc = (r & 3) + 8 * (r >> 2) + 4 * lh;
                float re = acc[i][j][r];
                float im = acc[i][j][r + 8];
                int bin = group * 16 + mloc;
                if (bin == 0) {
                    outb[t] = sqrtf(fmaxf(re * re, 1e-12f));
                    outb[(long long)512 * T_FRAMES + t] = sqrtf(fmaxf(im * im, 1e-12f));
                } else {
                    outb[(long long)bin * T_FRAMES + t] =
                        sqrtf(fmaxf(re * re + im * im, 1e-12f));
                }
            }
        }
    }
}

extern "C" void kernel_launch(void* const* d_in, const int* in_sizes, int n_in,
                              void* d_out, int out_size, void* d_ws, size_t ws_size,
                              hipStream_t stream) {
    const float* x  = (const float*)d_in[0];
    const float* wt = (const float*)d_in[1];
    float* out = (float*)d_out;

    unsigned short* Xb = (unsigned short*)d_ws;                             // 16.04 MiB
    unsigned short* Wb = (unsigned short*)((char*)d_ws + (size_t)33554432); // 2 MiB

    prep<<<4608, 256, 0, stream>>>(x, wt, Xb, Wb);
    stft_gemm<<<2048, 256, 0, stream>>>(Xb, Wb, out);
}

// Round 5
// 160.593 us; speedup vs baseline: 1.0113x; 1.0113x over previous
//
#include <hip/hip_runtime.h>
#include <stdint.h>

#define SAMPLES   524288
#define BATCH     16
#define T_FRAMES  2048
#define K_FFT     1024
#define HOPSZ     256
#define CACHEPAD  1023
#define NCH       513
#define XROW      525312               // 1023 pad + 524288 samples + 1 spare (16B-aligned rows)

typedef __bf16          bf16x8 __attribute__((ext_vector_type(8)));
typedef float           f32x4  __attribute__((ext_vector_type(4)));
typedef float           f32x16 __attribute__((ext_vector_type(16)));
typedef unsigned short  u16x8  __attribute__((ext_vector_type(8)));

__device__ __forceinline__ unsigned short f2bf(float f) {
    union { float f; unsigned u; } v; v.f = f;
    unsigned r = v.u + 0x7fffu + ((v.u >> 16) & 1u);   // round-to-nearest-even
    return (unsigned short)(r >> 16);
}

// ---------- fused prep ----------------------------------------------------
// blocks [0,512):    weight fp32 -> bf16, M=1024 layout: per 32-row group q:
//                    {16 cos rows of bins q*16+r | 16 sin rows}; sin(bin0)
//                    slot holds cos(bin 512) (sin0 == 0, sin512 == 0).
// blocks [512,4608): x fp32 -> bf16, 1023-zero left pad. Store window shifted
//                    +1 sample so dst is 16B-aligned -> one u16x8 store per
//                    thread (sample 0 scalar once per row; tail writes the
//                    never-read spare slot).
__global__ void prep(const float* __restrict__ x, const float* __restrict__ wsrc,
                     unsigned short* __restrict__ Xb, unsigned short* __restrict__ Wb) {
    const int bid = blockIdx.x;
    const int tid = threadIdx.x;
    if (bid < 512) {
        int gid = bid * 256 + tid;            // 0..131071, 8 u16 each
        int m   = gid >> 7;                   // 0..1023 output row
        int kc  = (gid & 127) << 3;           // k chunk base
        int q = m >> 5, h = (m >> 4) & 1, r = m & 15;
        int bin  = q * 16 + r;
        int srow = (h == 0) ? bin : (bin == 0 ? 512 : NCH + bin);
        const float* s = wsrc + (long long)srow * K_FFT + kc;
        f32x4 a = *(const f32x4*)s;
        f32x4 c = *(const f32x4*)(s + 4);
        union { u16x8 v; unsigned short e[8]; } o;
        o.e[0]=f2bf(a[0]); o.e[1]=f2bf(a[1]); o.e[2]=f2bf(a[2]); o.e[3]=f2bf(a[3]);
        o.e[4]=f2bf(c[0]); o.e[5]=f2bf(c[1]); o.e[6]=f2bf(c[2]); o.e[7]=f2bf(c[3]);
        *(u16x8*)(Wb + (long long)m * K_FFT + kc) = o.v;
    } else {
        int id  = bid - 512;
        int bat = id >> 8;
        int bx  = id & 255;
        unsigned short* xbo = Xb + (long long)bat * XROW;
        if (bx == 0) {
            for (int j = tid; j < CACHEPAD; j += 256) xbo[j] = 0;
        }
        int i0 = (bx * 256 + tid) * 8;
        const float* xb = x + (long long)bat * SAMPLES;
        f32x4 a = *(const f32x4*)&xb[i0];
        f32x4 c = *(const f32x4*)&xb[i0 + 4];
        float e = (i0 + 8 < SAMPLES) ? xb[i0 + 8] : 0.f;
        union { u16x8 v; unsigned short s[8]; } o;     // samples i0+1 .. i0+8
        o.s[0]=f2bf(a[1]); o.s[1]=f2bf(a[2]); o.s[2]=f2bf(a[3]);
        o.s[3]=f2bf(c[0]); o.s[4]=f2bf(c[1]); o.s[5]=f2bf(c[2]); o.s[6]=f2bf(c[3]);
        o.s[7]=f2bf(e);
        *(u16x8*)(xbo + 1024 + i0) = o.v;              // byte off 2048+16k: aligned
        if (i0 == 0) xbo[CACHEPAD] = f2bf(a[0]);       // sample 0
    }
}

// ---------- async global -> LDS (16 B/lane, dst = wave-uniform base + lane*16)
__device__ __forceinline__ void gll16(const unsigned short* g, unsigned short* s) {
    __builtin_amdgcn_global_load_lds(
        (const __attribute__((address_space(1))) void*)g,
        (__attribute__((address_space(3))) void*)s,
        16, 0, 0);
}

// ---------- main GEMM + magnitude epilogue --------------------------------
// Round-2 TLP structure (2-barrier 128x128 tile, 3 blocks/CU) + 32x32x16
// MFMA (half the issue slots/FLOP). Round-4 regression root-caused: swizzle
// chunk-const varied only per 32-lane half (g = s*2 + (l>>5)) -> octets 0-3
// identical chunk patterns -> 4 conflict-cyc per ds_read_b128 (8.4M = 2^23
// exactly). Fix: two-level XOR swizzle — store global chunk g of row r at
// lds chunk g ^ (r&7) ^ (((r>>3)&3)<<1). Staging side: (r>>3)&3 = (w*4+c)&3
// (wave-uniform, free). Read side: (row>>3)&3 = (l>>3)&3, so the reader
// chunk-const takes 8 DISTINCT values, one per octet (strictly more
// decorrelated than the proven round-2 pattern's 4-per-quad).
__global__ __launch_bounds__(256, 3)
void stft_gemm(const unsigned short* __restrict__ Xb,
               const unsigned short* __restrict__ Wb,
               float* __restrict__ out) {
    __shared__ unsigned short Ws[128 * 64];   // 16 KB
    __shared__ unsigned short Fs[128 * 64];   // 16 KB

    const int id  = blockIdx.x;
    const int xcd = id & 7;
    const int idx = id >> 3;        // 0..255
    const int nt  = idx >> 5;       // 0..7  M tile (32 consecutive blocks share it)
    const int ft  = (xcd << 5) | (idx & 31);   // 0..255 frame tile, striped per XCD

    const int tid = threadIdx.x;
    const int l   = tid & 63;
    const int w   = tid >> 6;

    const int b  = ft >> 4;
    const int t0 = (ft & 15) * 128;            // frame tile never crosses a batch

    const unsigned short* xbase = Xb + (long long)b * XROW;

    // ---- staging: wave w stages rows [w*32, w*32+32) of Fs and Ws,
    //      4 gll16 calls each; call c: row = w*32 + c*8 + (l>>3),
    //      lds chunk = l&7 (implicit dst),
    //      global chunk = (l&7) ^ (r&7) ^ (((r>>3)&3)<<1)
    //                   = (l&7) ^ (l>>3) ^ (((w*4+c)&3)<<1).
    const int srow   = l >> 3;
    const int schunk = l & 7;

    const unsigned short* fsrc[4];
    const unsigned short* wsrc[4];
    unsigned short* fdst[4];
    unsigned short* wdst[4];
    #pragma unroll
    for (int c = 0; c < 4; ++c) {
        int r = w * 32 + c * 8 + srow;
        int gchunk = schunk ^ srow ^ (((w * 4 + c) & 3) << 1);
        fsrc[c] = xbase + (t0 + r) * HOPSZ + gchunk * 8;       // frame r, k-chunk
        wsrc[c] = Wb + ((long long)(nt * 128 + r)) * K_FFT + gchunk * 8;
        fdst[c] = Fs + (w * 32 + c * 8) * 64;
        wdst[c] = Ws + (w * 32 + c * 8) * 64;
    }

    const int wave_m = w & 1;
    const int wave_n = w >> 1;
    const int l31 = l & 31;
    const int lh  = l >> 5;

    f32x16 acc[2][2];
    #pragma unroll
    for (int i = 0; i < 2; ++i)
        #pragma unroll
        for (int j = 0; j < 2; ++j)
            acc[i][j] = (f32x16){0.f,0.f,0.f,0.f,0.f,0.f,0.f,0.f,
                                 0.f,0.f,0.f,0.f,0.f,0.f,0.f,0.f};

    // ds_read: row = base + l31 (row&7 = l&7, (row>>3)&3 = (l>>3)&3);
    // wanted global chunk g = s*2 + lh ->
    // lds chunk = g ^ (l&7) ^ (((l>>3)&3)<<1)
    int a_off[2][4], b_off[2][4];
    #pragma unroll
    for (int i = 0; i < 2; ++i)
        #pragma unroll
        for (int s = 0; s < 4; ++s) {
            int ck = ((s * 2 + lh) ^ (l & 7) ^ (((l >> 3) & 3) << 1)) * 8;
            a_off[i][s] = (wave_m * 64 + i * 32 + l31) * 64 + ck;
            b_off[i][s] = (wave_n * 64 + i * 32 + l31) * 64 + ck;
        }

    for (int kk = 0; kk < K_FFT; kk += 64) {
        #pragma unroll
        for (int c = 0; c < 4; ++c) gll16(fsrc[c] + kk, fdst[c]);
        #pragma unroll
        for (int c = 0; c < 4; ++c) gll16(wsrc[c] + kk, wdst[c]);
        __syncthreads();

        #pragma unroll
        for (int s = 0; s < 4; ++s) {          // 4 k-slices of 16
            bf16x8 a0 = *(const bf16x8*)&Ws[a_off[0][s]];
            bf16x8 a1 = *(const bf16x8*)&Ws[a_off[1][s]];
            bf16x8 b0 = *(const bf16x8*)&Fs[b_off[0][s]];
            bf16x8 b1 = *(const bf16x8*)&Fs[b_off[1][s]];
            acc[0][0] = __builtin_amdgcn_mfma_f32_32x32x16_bf16(a0, b0, acc[0][0], 0, 0, 0);
            acc[0][1] = __builtin_amdgcn_mfma_f32_32x32x16_bf16(a0, b1, acc[0][1], 0, 0, 0);
            acc[1][0] = __builtin_amdgcn_mfma_f32_32x32x16_bf16(a1, b0, acc[1][0], 0, 0, 0);
            acc[1][1] = __builtin_amdgcn_mfma_f32_32x32x16_bf16(a1, b1, acc[1][1], 0, 0, 0);
        }
        __syncthreads();
    }

    // ---- epilogue: mag = sqrt(max(re^2+im^2, 1e-12)) ----------------------
    // frag (i,j): 32-row group = nt*4 + wave_m*2 + i ({16 cos | 16 sin});
    // lane: frame = l31, reg r<8: cos row mloc=(r&3)+8*(r>>2)+4*lh,
    // reg r+8: sin row mloc+16. bin0 slot: re->bin0, im(=cos512)->bin512.
    float* outb = out + (long long)b * (NCH * T_FRAMES);
    #pragma unroll
    for (int i = 0; i < 2; ++i) {
        const int group = nt * 4 + wave_m * 2 + i;
        #pragma unroll
        for (int j = 0; j < 2; ++j) {
            const int t = t0 + wave_n * 64 + j * 32 + l31;
            #pragma unroll
            for (int r = 0; r < 8; ++r) {
                const int mloc = (r & 3) + 8 * (r >> 2) + 4 * lh;
                float re = acc[i][j][r];
                float im = acc[i][j][r + 8];
                int bin = group * 16 + mloc;
                if (bin == 0) {
                    outb[t] = sqrtf(fmaxf(re * re, 1e-12f));
                    outb[(long long)512 * T_FRAMES + t] = sqrtf(fmaxf(im * im, 1e-12f));
                } else {
                    outb[(long long)bin * T_FRAMES + t] =
                        sqrtf(fmaxf(re * re + im * im, 1e-12f));
                }
            }
        }
    }
}

extern "C" void kernel_launch(void* const* d_in, const int* in_sizes, int n_in,
                              void* d_out, int out_size, void* d_ws, size_t ws_size,
                              hipStream_t stream) {
    const float* x  = (const float*)d_in[0];
    const float* wt = (const float*)d_in[1];
    float* out = (float*)d_out;

    unsigned short* Xb = (unsigned short*)d_ws;                             // 16.04 MiB
    unsigned short* Wb = (unsigned short*)((char*)d_ws + (size_t)33554432); // 2 MiB

    prep<<<4608, 256, 0, stream>>>(x, wt, Xb, Wb);
    stft_gemm<<<2048, 256, 0, stream>>>(Xb, Wb, out);
}

// Round 6
// 154.236 us; speedup vs baseline: 1.0530x; 1.0412x over previous
//
#include <hip/hip_runtime.h>
#include <stdint.h>

#define SAMPLES   524288
#define BATCH     16
#define T_FRAMES  2048
#define K_FFT     1024
#define HOPSZ     256
#define CACHEPAD  1023
#define NCH       513
#define XROW      525312               // 1023 pad + 524288 samples + 1 spare (16B-aligned rows)

typedef __bf16          bf16x8 __attribute__((ext_vector_type(8)));
typedef float           f32x4  __attribute__((ext_vector_type(4)));
typedef unsigned short  u16x8  __attribute__((ext_vector_type(8)));

__device__ __forceinline__ unsigned short f2bf(float f) {
    union { float f; unsigned u; } v; v.f = f;
    unsigned r = v.u + 0x7fffu + ((v.u >> 16) & 1u);   // round-to-nearest-even
    return (unsigned short)(r >> 16);
}

// ---------- fused prep (weight layout r1-r5; vectorized x-store r4-r5) ----
// blocks [0,512):    weight fp32 -> bf16, M=1024 layout: per 32-row group q:
//                    {16 cos rows of bins q*16+r | 16 sin rows}; sin(bin0)
//                    slot holds cos(bin 512) (sin0 == 0, sin512 == 0).
// blocks [512,4608): x fp32 -> bf16, 1023-zero left pad. Store window shifted
//                    +1 sample so dst is 16B-aligned -> one u16x8 store per
//                    thread (sample 0 scalar once per row; tail writes the
//                    never-read spare slot).
__global__ void prep(const float* __restrict__ x, const float* __restrict__ wsrc,
                     unsigned short* __restrict__ Xb, unsigned short* __restrict__ Wb) {
    const int bid = blockIdx.x;
    const int tid = threadIdx.x;
    if (bid < 512) {
        int gid = bid * 256 + tid;            // 0..131071, 8 u16 each
        int m   = gid >> 7;                   // 0..1023 output row
        int kc  = (gid & 127) << 3;           // k chunk base
        int q = m >> 5, h = (m >> 4) & 1, r = m & 15;
        int bin  = q * 16 + r;
        int srow = (h == 0) ? bin : (bin == 0 ? 512 : NCH + bin);
        const float* s = wsrc + (long long)srow * K_FFT + kc;
        f32x4 a = *(const f32x4*)s;
        f32x4 c = *(const f32x4*)(s + 4);
        union { u16x8 v; unsigned short e[8]; } o;
        o.e[0]=f2bf(a[0]); o.e[1]=f2bf(a[1]); o.e[2]=f2bf(a[2]); o.e[3]=f2bf(a[3]);
        o.e[4]=f2bf(c[0]); o.e[5]=f2bf(c[1]); o.e[6]=f2bf(c[2]); o.e[7]=f2bf(c[3]);
        *(u16x8*)(Wb + (long long)m * K_FFT + kc) = o.v;
    } else {
        int id  = bid - 512;
        int bat = id >> 8;
        int bx  = id & 255;
        unsigned short* xbo = Xb + (long long)bat * XROW;
        if (bx == 0) {
            for (int j = tid; j < CACHEPAD; j += 256) xbo[j] = 0;
        }
        int i0 = (bx * 256 + tid) * 8;
        const float* xb = x + (long long)bat * SAMPLES;
        f32x4 a = *(const f32x4*)&xb[i0];
        f32x4 c = *(const f32x4*)&xb[i0 + 4];
        float e = (i0 + 8 < SAMPLES) ? xb[i0 + 8] : 0.f;
        union { u16x8 v; unsigned short s[8]; } o;     // samples i0+1 .. i0+8
        o.s[0]=f2bf(a[1]); o.s[1]=f2bf(a[2]); o.s[2]=f2bf(a[3]);
        o.s[3]=f2bf(c[0]); o.s[4]=f2bf(c[1]); o.s[5]=f2bf(c[2]); o.s[6]=f2bf(c[3]);
        o.s[7]=f2bf(e);
        *(u16x8*)(xbo + 1024 + i0) = o.v;              // byte off 2048+16k: aligned
        if (i0 == 0) xbo[CACHEPAD] = f2bf(a[0]);       // sample 0
    }
}

// ---------- async global -> LDS (16 B/lane, dst = wave-uniform base + lane*16)
__device__ __forceinline__ void gll16(const unsigned short* g, unsigned short* s) {
    __builtin_amdgcn_global_load_lds(
        (const __attribute__((address_space(1))) void*)g,
        (__attribute__((address_space(3))) void*)s,
        16, 0, 0);
}

// ---------- main GEMM + magnitude epilogue --------------------------------
// Round-2 proven kernel (954 TF, 72.0 us, 0 bank conflicts): high-TLP
// 2-barrier 128x128 tile, 16x16x32 MFMA, 3 blocks/CU. Session ledger:
//  - 8-phase 256^2 1-block/CU (r1, r3 persistent): 81 us both — TLP > deep
//    pipeline on this 16-K-tile shape.
//  - 32x32x16 MFMA (r4, r5 two swizzles): 79-81 us, deterministic 4 cyc
//    bank conflict per ds_read_b128 regardless of XOR const (mechanism tied
//    to the row=l&31 fragment shape, not chunk balance) — shape abandoned.
// LDS [row][64] u16, chunk swizzle: global chunk (l&7)^(row&7) stored at
// lds chunk l&7; read chunk-const varies per 16-lane quad (qd) -> 0 conflicts.
__global__ __launch_bounds__(256, 3)
void stft_gemm(const unsigned short* __restrict__ Xb,
               const unsigned short* __restrict__ Wb,
               float* __restrict__ out) {
    __shared__ unsigned short Ws[128 * 64];   // 16 KB
    __shared__ unsigned short Fs[128 * 64];   // 16 KB

    const int id  = blockIdx.x;
    const int xcd = id & 7;
    const int idx = id >> 3;        // 0..255
    const int nt  = idx >> 5;       // 0..7  M tile (32 consecutive blocks share it)
    const int ft  = (xcd << 5) | (idx & 31);   // 0..255 frame tile, striped per XCD

    const int tid = threadIdx.x;
    const int l   = tid & 63;
    const int w   = tid >> 6;
    const int ln  = l & 15;
    const int qd  = l >> 4;

    const int b  = ft >> 4;
    const int t0 = (ft & 15) * 128;            // frame tile never crosses a batch

    const unsigned short* xbase = Xb + (long long)b * XROW;

    // ---- staging: wave w stages rows [w*32, w*32+32) of Fs and Ws,
    //      4 gll16 calls each; call c: row = w*32 + c*8 + (l>>3),
    //      lds chunk = l&7 (implicit dst), global chunk = (l&7) ^ (row&7).
    const int srow   = l >> 3;
    const int schunk = l & 7;

    const unsigned short* fsrc[4];
    const unsigned short* wsrc[4];
    unsigned short* fdst[4];
    unsigned short* wdst[4];
    #pragma unroll
    for (int c = 0; c < 4; ++c) {
        int r = w * 32 + c * 8 + srow;
        int gchunk = schunk ^ (r & 7);
        fsrc[c] = xbase + (t0 + r) * HOPSZ + gchunk * 8;       // frame r, k-chunk
        wsrc[c] = Wb + ((long long)(nt * 128 + r)) * K_FFT + gchunk * 8;
        fdst[c] = Fs + (w * 32 + c * 8) * 64;
        wdst[c] = Ws + (w * 32 + c * 8) * 64;
    }

    const int wave_m = w & 1;
    const int wave_n = w >> 1;

    f32x4 acc[4][4];
    #pragma unroll
    for (int i = 0; i < 4; ++i)
        #pragma unroll
        for (int j = 0; j < 4; ++j)
            acc[i][j] = (f32x4){0.f, 0.f, 0.f, 0.f};

    // ds_read offsets: row = base + i*16 + ln (row&7 == ln&7);
    // global chunk wanted = k2*4 + qd -> lds chunk = (k2*4+qd) ^ (ln&7)
    int a_off[4][2], b_off[4][2];
    #pragma unroll
    for (int i = 0; i < 4; ++i)
        #pragma unroll
        for (int k2 = 0; k2 < 2; ++k2) {
            int ck = ((k2 * 4 + qd) ^ (ln & 7)) * 8;
            a_off[i][k2] = (wave_m * 64 + i * 16 + ln) * 64 + ck;
            b_off[i][k2] = (wave_n * 64 + i * 16 + ln) * 64 + ck;
        }

    for (int kk = 0; kk < K_FFT; kk += 64) {
        #pragma unroll
        for (int c = 0; c < 4; ++c) gll16(fsrc[c] + kk, fdst[c]);
        #pragma unroll
        for (int c = 0; c < 4; ++c) gll16(wsrc[c] + kk, wdst[c]);
        __syncthreads();

        #pragma unroll
        for (int k2 = 0; k2 < 2; ++k2) {
            bf16x8 av[4], bv[4];
            #pragma unroll
            for (int i = 0; i < 4; ++i) av[i] = *(const bf16x8*)&Ws[a_off[i][k2]];
            #pragma unroll
            for (int j = 0; j < 4; ++j) bv[j] = *(const bf16x8*)&Fs[b_off[j][k2]];
            #pragma unroll
            for (int i = 0; i < 4; ++i)
                #pragma unroll
                for (int j = 0; j < 4; ++j)
                    acc[i][j] = __builtin_amdgcn_mfma_f32_16x16x32_bf16(av[i], bv[j], acc[i][j], 0, 0, 0);
        }
        __syncthreads();
    }

    // ---- epilogue: mag = sqrt(max(re^2+im^2, 1e-12)), coalesced stores ----
    // D layout (16x16x32): frame = lane&15, m-sub = qd*4 + reg.
    // A-frag i = 2p+h: h=0 cos, h=1 sin of bin group q = nt*4 + wave_m*2 + p.
    // bin==0 slot: re -> bin 0, im (= cos512 row) -> bin 512.
    float* outb = out + (long long)b * (NCH * T_FRAMES);
    #pragma unroll
    for (int p = 0; p < 2; ++p) {
        #pragma unroll
        for (int j = 0; j < 4; ++j) {
            const int t = t0 + wave_n * 64 + j * 16 + ln;
            #pragma unroll
            for (int r = 0; r < 4; ++r) {
                float re  = acc[2 * p][j][r];
                float im  = acc[2 * p + 1][j][r];
                int bin = (nt * 4 + wave_m * 2 + p) * 16 + qd * 4 + r;
                if (bin == 0) {
                    outb[t] = sqrtf(fmaxf(re * re, 1e-12f));
                    outb[(long long)512 * T_FRAMES + t] = sqrtf(fmaxf(im * im, 1e-12f));
                } else {
                    outb[(long long)bin * T_FRAMES + t] =
                        sqrtf(fmaxf(re * re + im * im, 1e-12f));
                }
            }
        }
    }
}

extern "C" void kernel_launch(void* const* d_in, const int* in_sizes, int n_in,
                              void* d_out, int out_size, void* d_ws, size_t ws_size,
                              hipStream_t stream) {
    const float* x  = (const float*)d_in[0];
    const float* wt = (const float*)d_in[1];
    float* out = (float*)d_out;

    unsigned short* Xb = (unsigned short*)d_ws;                             // 16.04 MiB
    unsigned short* Wb = (unsigned short*)((char*)d_ws + (size_t)33554432); // 2 MiB

    prep<<<4608, 256, 0, stream>>>(x, wt, Xb, Wb);
    stft_gemm<<<2048, 256, 0, stream>>>(Xb, Wb, out);
}